// Round 1
// 1712.938 us; speedup vs baseline: 1.9514x; 1.9514x over previous
//
#include <hip/hip_runtime.h>

// ---------------- problem constants ----------------
#define BB 16
#define SS 100
#define HH 400      // hidden per direction
#define H2 800
#define G4 1600     // 4*H gate rows
#define DIN0 150    // WE+PE

// ---------------- workspace layout (float offsets) ----------------
#define OFF_X0   0ULL          // 240,000
#define OFF_GF   240000ULL     // 2,560,000 (g0f / g1f / ua)
#define OFF_GB   2800000ULL    // 2,560,000 (g0b / g1b / wa)
#define OFF_H1   5360000ULL    // 1,280,000
#define OFF_OUT2 6640000ULL    // 1,280,000
#define OFF_SC   7920000ULL    // 158,400
#define OFF_NLL  8078400ULL    // 1,600
#define OFF_CNT  8080000ULL    // 1,600 ints
#define OFF_EXH  8081600ULL    // u16 exchange planes start (128B aligned)
#define EX_U16_PER_PLANE 1331200ULL   // 2 dir * 100 steps * 13 kt * 64 * 8

typedef _Float16 f16x8 __attribute__((ext_vector_type(8)));
typedef float    f32x4 __attribute__((ext_vector_type(4)));

// ---------------- embedding ----------------
__global__ __launch_bounds__(256) void embed_kernel(
    const int* __restrict__ tok, const int* __restrict__ pos,
    const float* __restrict__ wW, const float* __restrict__ pW,
    float* __restrict__ x0)
{
    int idx = blockIdx.x * 256 + threadIdx.x;
    if (idx >= BB * SS * DIN0) return;
    int n = idx / DIN0, d = idx % DIN0;
    x0[idx] = (d < 100) ? wW[tok[n] * 100 + d] : pW[pos[n] * 50 + (d - 100)];
}

// ---------------- generic NT GEMM: C[n][r] = bias[r] + sum_k A[n][k]*W[r][k] ----------------
__global__ __launch_bounds__(256) void gemm_nt_bias(
    const float* __restrict__ A, const float* __restrict__ W,
    const float* __restrict__ bias, float* __restrict__ C,
    int N, int K, int R)
{
    __shared__ __attribute__((aligned(16))) float As[16][68];
    __shared__ __attribute__((aligned(16))) float Ws[16][68];
    int tid = threadIdx.x;
    int tx = tid & 15, ty = tid >> 4;
    int row0 = blockIdx.y * 64, col0 = blockIdx.x * 64;
    float acc[4][4];
#pragma unroll
    for (int i = 0; i < 4; i++)
#pragma unroll
        for (int j = 0; j < 4; j++) acc[i][j] = 0.f;

    int ktiles = (K + 15) >> 4;
    for (int kt = 0; kt < ktiles; kt++) {
        int kb = kt << 4;
#pragma unroll
        for (int e = 0; e < 4; e++) {
            int i = tid + (e << 8);
            int r = i >> 4, kk = i & 15;
            int gk = kb + kk;
            As[kk][r] = (row0 + r < N && gk < K) ? A[(size_t)(row0 + r) * K + gk] : 0.f;
            Ws[kk][r] = (col0 + r < R && gk < K) ? W[(size_t)(col0 + r) * K + gk] : 0.f;
        }
        __syncthreads();
#pragma unroll
        for (int kk = 0; kk < 16; kk++) {
            float4 av = *(const float4*)&As[kk][ty * 4];
            float4 wv = *(const float4*)&Ws[kk][tx * 4];
            float a[4] = {av.x, av.y, av.z, av.w};
            float w[4] = {wv.x, wv.y, wv.z, wv.w};
#pragma unroll
            for (int i = 0; i < 4; i++)
#pragma unroll
                for (int j = 0; j < 4; j++) acc[i][j] = fmaf(a[i], w[j], acc[i][j]);
        }
        __syncthreads();
    }
#pragma unroll
    for (int i = 0; i < 4; i++) {
        int gr = row0 + ty * 4 + i;
        if (gr >= N) continue;
        int gc = col0 + tx * 4;
        if (gc >= R) continue;
        float4 o;
        o.x = acc[i][0] + (bias ? bias[gc + 0] : 0.f);
        o.y = acc[i][1] + (bias ? bias[gc + 1] : 0.f);
        o.z = acc[i][2] + (bias ? bias[gc + 2] : 0.f);
        o.w = acc[i][3] + (bias ? bias[gc + 3] : 0.f);
        *(float4*)&C[(size_t)gr * R + gc] = o;
    }
}

// ---------------- LSTM recurrence: MFMA f16 hi/lo split, LLC-atomic h exchange ----------------
// 100 WGs/dir x 64 threads. Each WG owns 4 hidden units (16 gate rows) x 16 batches
// = one 16x16 MFMA D-tile. K=400 padded to 416 = 13 k-tiles of 32.
// Weights LDS-resident as f16 hi/lo fragments (lo pre-scaled x2048, fp32-equivalent total).
// Per-step h exchanged via agent-scope atomic u32 stores to per-step LLC buffers
// (bypass non-coherent per-XCD L2; no acquire-invalidate needed: first-touch reads).
__global__ __launch_bounds__(64, 1) void lstm_layer_kernel(
    const float* __restrict__ Gf, const float* __restrict__ Gb,
    const float* __restrict__ Wf, const float* __restrict__ Wb,
    float* __restrict__ hbuf,          // [B][S][800] fp32 for downstream kernels
    int* __restrict__ cnt,             // [2][100][4] step counters
    unsigned short* __restrict__ exhi, // f16 hi plane, frag layout [dir][s][kt][64][8]
    unsigned short* __restrict__ exlo) // f16 lo plane (x2048)
{
    const int dir = blockIdx.x / 100;
    const int wg  = blockIdx.x % 100;
    const int j0  = wg * 4;
    const float* __restrict__ G = dir ? Gb : Gf;
    const float* __restrict__ W = dir ? Wb : Wf;

    const int l   = threadIdx.x;   // 0..63
    const int b   = l & 15;
    const int hi4 = l >> 4;

    __shared__ __attribute__((aligned(16))) unsigned short ahi[13 * 64 * 8];
    __shared__ __attribute__((aligned(16))) unsigned short alo[13 * 64 * 8];
    __shared__ float gl[16 * 17];

    // ---- one-time: weights -> f16 hi/lo A-fragments in LDS ----
    // A[m][k]: m = lane&15 (local gate row r = 4*g + jj), k = kt*32 + (lane>>4)*8 + e
    {
        const int m = b;
        const int g = m >> 2, jj = m & 3;
        const float* wrow = W + (size_t)(g * HH + j0 + jj) * HH;
        for (int kt = 0; kt < 13; kt++) {
            for (int e = 0; e < 8; e++) {
                int k = kt * 32 + hi4 * 8 + e;
                float w = (k < HH) ? wrow[k] : 0.f;
                _Float16 wh = (_Float16)w;
                _Float16 wl = (_Float16)((w - (float)wh) * 2048.f);
                ahi[(kt * 64 + l) * 8 + e] = __builtin_bit_cast(unsigned short, wh);
                alo[(kt * 64 + l) * 8 + e] = __builtin_bit_cast(unsigned short, wl);
            }
        }
    }
    __syncthreads();

    float c_reg = 0.f;
    unsigned short* exh_d = exhi + (size_t)dir * 100 * 13 * 512;
    unsigned short* exl_d = exlo + (size_t)dir * 100 * 13 * 512;

    for (int s = 0; s < SS; s++) {
        const int time = dir ? (SS - 1 - s) : s;
        // prefetch input-projection gates: rows 4*hi4..+3 (gate=hi4, jj=0..3), col b
        f32x4 gpre = *(const f32x4*)&G[(size_t)(b * SS + time) * G4 + hi4 * HH + j0];

        f32x4 acc;
        if (s > 0) {
            // wait for all 100 producers of this direction at step s-1
            int* c4 = cnt + (dir * 100 + (s - 1)) * 4;
            for (int guard = 0; guard < (1 << 20); guard++) {
                int sum = 0;
                if (l == 0) {
                    sum  = __hip_atomic_load(c4 + 0, __ATOMIC_RELAXED, __HIP_MEMORY_SCOPE_AGENT);
                    sum += __hip_atomic_load(c4 + 1, __ATOMIC_RELAXED, __HIP_MEMORY_SCOPE_AGENT);
                    sum += __hip_atomic_load(c4 + 2, __ATOMIC_RELAXED, __HIP_MEMORY_SCOPE_AGENT);
                    sum += __hip_atomic_load(c4 + 3, __ATOMIC_RELAXED, __HIP_MEMORY_SCOPE_AGENT);
                }
                if (__ballot(sum >= 100) & 1ull) break;
                __builtin_amdgcn_s_sleep(1);
            }
            asm volatile("" ::: "memory");   // no load hoisting above the poll

            // B-fragments straight from global (coalesced b128, LLC/L2-served)
            const f16x8* __restrict__ pbh = (const f16x8*)(exh_d + (size_t)(s - 1) * 13 * 512);
            const f16x8* __restrict__ pbl = (const f16x8*)(exl_d + (size_t)(s - 1) * 13 * 512);
            f16x8 bh[13], bl[13];
#pragma unroll
            for (int kt = 0; kt < 13; kt++) {
                bh[kt] = pbh[kt * 64 + l];
                bl[kt] = pbl[kt * 64 + l];
            }
            f32x4 aHH = gpre;
            f32x4 aHL = {0.f, 0.f, 0.f, 0.f};
            f32x4 aLH = {0.f, 0.f, 0.f, 0.f};
#pragma unroll
            for (int kt = 0; kt < 13; kt++) {
                f16x8 wh = *(const f16x8*)&ahi[(kt * 64 + l) * 8];
                f16x8 wl = *(const f16x8*)&alo[(kt * 64 + l) * 8];
                aHH = __builtin_amdgcn_mfma_f32_16x16x32_f16(wh, bh[kt], aHH, 0, 0, 0);
                aHL = __builtin_amdgcn_mfma_f32_16x16x32_f16(wh, bl[kt], aHL, 0, 0, 0);
                aLH = __builtin_amdgcn_mfma_f32_16x16x32_f16(wl, bh[kt], aLH, 0, 0, 0);
            }
            acc = aHH + (aHL + aLH) * (1.f / 2048.f);
        } else {
            acc = gpre;   // h(-1) = 0
        }

        // D lane l holds rows 4*hi4+q, col b -> scatter so lane (jj,b) gets its 4 gates
#pragma unroll
        for (int q = 0; q < 4; q++) gl[(4 * hi4 + q) * 17 + b] = acc[q];
        __syncthreads();

        const int jj = hi4;             // cell-phase role: hidden jj, batch b
        float gi = gl[( 0 + jj) * 17 + b];
        float gf = gl[( 4 + jj) * 17 + b];
        float gg = gl[( 8 + jj) * 17 + b];
        float go = gl[(12 + jj) * 17 + b];
        __syncthreads();                // gl reusable next step

        float si = 1.f / (1.f + expf(-gi));
        float sf = 1.f / (1.f + expf(-gf));
        float tg = tanhf(gg);
        float so = 1.f / (1.f + expf(-go));
        float c  = sf * c_reg + si * tg;
        c_reg = c;
        float h  = so * tanhf(c);

        hbuf[(size_t)(b * SS + time) * H2 + dir * HH + j0 + jj] = h;

        if (s < SS - 1) {
            // publish h as f16 hi/lo into B-fragment layout via LLC-bypass atomic u32s
            _Float16 hh = (_Float16)h;
            _Float16 hl = (_Float16)((h - (float)hh) * 2048.f);
            unsigned uh = __builtin_bit_cast(unsigned short, hh);
            unsigned ul = __builtin_bit_cast(unsigned short, hl);
            unsigned ph = uh | (((unsigned)__shfl_down((int)uh, 16)) << 16);
            unsigned pl = ul | (((unsigned)__shfl_down((int)ul, 16)) << 16);
            if ((jj & 1) == 0) {        // even jj stores the (k0, k0+1) pair
                int k0 = j0 + jj;
                int kt = k0 >> 5, ko = k0 & 31;
                int lg = ko >> 3, e = ko & 7;   // e even by construction
                size_t u16idx = ((size_t)(s * 13 + kt) * 64 + (lg * 16 + b)) * 8 + e;
                __hip_atomic_store((unsigned*)(exh_d + u16idx), ph,
                                   __ATOMIC_RELAXED, __HIP_MEMORY_SCOPE_AGENT);
                __hip_atomic_store((unsigned*)(exl_d + u16idx), pl,
                                   __ATOMIC_RELAXED, __HIP_MEMORY_SCOPE_AGENT);
            }
            // stores ACK'd at LLC before the counter inc becomes visible
            asm volatile("s_waitcnt vmcnt(0)" ::: "memory");
            if (l == 0)
                __hip_atomic_fetch_add(cnt + (dir * 100 + s) * 4 + (wg & 3), 1,
                                       __ATOMIC_RELAXED, __HIP_MEMORY_SCOPE_AGENT);
        }
    }
}

// ---------------- attention scores ----------------
#define ITILE 11
__global__ __launch_bounds__(256) void attn_scores_kernel(
    const float* __restrict__ ua, const float* __restrict__ wa,
    const float* __restrict__ va, float* __restrict__ scores)
{
    int b  = blockIdx.x / 9;
    int i0 = (blockIdx.x % 9) * ITILE;
    int tid = threadIdx.x;
    __shared__ float ua_t[100][101];
    __shared__ float wa_t[ITILE][102];
    __shared__ float sacc[ITILE][101];
    __shared__ float va_t[100];

    for (int p = tid; p < ITILE * 101; p += 256) ((float*)sacc)[p] = 0.f;

    for (int ht = 0; ht < 8; ht++) {
        int h0 = ht * 100;
        __syncthreads();
        for (int p = tid; p < 100 * 100; p += 256) {
            int j = p / 100, hh = p % 100;
            ua_t[j][hh] = ua[(size_t)(b * SS + j) * H2 + h0 + hh];
        }
        for (int p = tid; p < ITILE * 100; p += 256) {
            int il = p / 100, hh = p % 100;
            wa_t[il][hh] = wa[(size_t)(b * SS + i0 + il + 1) * H2 + h0 + hh];
        }
        if (tid < 100) va_t[tid] = va[h0 + tid];
        __syncthreads();
        for (int p = tid; p < ITILE * 100; p += 256) {
            int il = p / 100, j = p % 100;
            float acc = 0.f;
#pragma unroll 4
            for (int hh = 0; hh < 100; hh++) {
                float x = ua_t[j][hh] + wa_t[il][hh];
                float z = __expf(2.f * x);
                float th = 1.f - 2.f * __builtin_amdgcn_rcpf(z + 1.f);
                acc = fmaf(th, va_t[hh], acc);
            }
            sacc[il][j] += acc;
        }
    }
    __syncthreads();
    for (int p = tid; p < ITILE * 100; p += 256) {
        int il = p / 100, j = p % 100;
        scores[(size_t)(b * 99 + i0 + il) * 100 + j] = sacc[il][j];
    }
}

// ---------------- softmax / table / preds / nll per (b,i) row ----------------
__global__ __launch_bounds__(128) void attn_softmax_kernel(
    const float* __restrict__ scores, const float* __restrict__ out2,
    const int* __restrict__ head, float* __restrict__ outb,
    float* __restrict__ nll)
{
    int bi = blockIdx.x;           // b*99 + i
    int b = bi / 99, i = bi % 99;
    int j = threadIdx.x;
    __shared__ float sv[128];
    __shared__ int   si[128];
    __shared__ float red[128];

    float h_t = out2[(size_t)(b * SS + i + 1) * H2];
    float sj = -1e30f;
    if (j < 100) {
        sj = scores[(size_t)bi * 100 + j];
        float h_j = out2[(size_t)(b * SS + j) * H2];
        if (h_j == h_t) sj = -10000.0f;
    }
    sv[j] = sj; si[j] = j;
    __syncthreads();
    for (int off = 64; off >= 1; off >>= 1) {
        if (j < off) {
            float o = sv[j + off]; int oi = si[j + off];
            if (o > sv[j] || (o == sv[j] && oi < si[j])) { sv[j] = o; si[j] = oi; }
        }
        __syncthreads();
    }
    float m = sv[0]; int amax = si[0];
    __syncthreads();
    float e = (j < 100) ? __expf(sj - m) : 0.f;
    red[j] = e;
    __syncthreads();
    for (int off = 64; off >= 1; off >>= 1) {
        if (j < off) red[j] += red[j + off];
        __syncthreads();
    }
    float sum = red[0];
    float inv = 1.f / sum;
    if (j < 100) outb[1 + 1584 + (size_t)bi * 100 + j] = e * inv;
    if (j == 0) {
        outb[1 + bi] = (float)amax;
        int gold = head[b * SS + i + 1];
        bool valid = (gold != -1);
        int gc = gold < 0 ? 0 : (gold > 99 ? 99 : gold);
        float sgc = scores[(size_t)bi * 100 + gc];
        float hgc = out2[(size_t)(b * SS + gc) * H2];
        if (hgc == h_t) sgc = -10000.0f;
        nll[bi] = valid ? -(sgc - m - logf(sum)) : 0.f;
    }
}

// ---------------- final loss reduction ----------------
__global__ __launch_bounds__(128) void loss_kernel(
    const float* __restrict__ nll, const int* __restrict__ head,
    float* __restrict__ outb)
{
    __shared__ float red[128];
    int tid = threadIdx.x;
    float contrib = 0.f;
    if (tid < 99) {
        int i = tid;
        float tot = 0.f; int cv = 0;
        for (int b = 0; b < BB; b++) {
            tot += nll[b * 99 + i];
            cv += (head[b * SS + i + 1] != -1) ? 1 : 0;
        }
        int denom = cv > 0 ? cv : 1;
        contrib = tot / (float)denom;
    }
    red[tid] = contrib;
    __syncthreads();
    for (int off = 64; off >= 1; off >>= 1) {
        if (tid < off) red[tid] += red[tid + off];
        __syncthreads();
    }
    if (tid == 0) outb[0] = red[0];
}

// ---------------- launch ----------------
extern "C" void kernel_launch(void* const* d_in, const int* in_sizes, int n_in,
                              void* d_out, int out_size, void* d_ws, size_t ws_size,
                              hipStream_t stream) {
    const int*   tok     = (const int*)d_in[0];
    const int*   pos     = (const int*)d_in[1];
    const int*   head    = (const int*)d_in[2];
    const float* word_W  = (const float*)d_in[3];
    const float* pos_W   = (const float*)d_in[4];
    const float* l0f_Wih = (const float*)d_in[5];
    const float* l0f_Whh = (const float*)d_in[6];
    const float* l0f_b   = (const float*)d_in[7];
    const float* l0b_Wih = (const float*)d_in[8];
    const float* l0b_Whh = (const float*)d_in[9];
    const float* l0b_b   = (const float*)d_in[10];
    const float* l1f_Wih = (const float*)d_in[11];
    const float* l1f_Whh = (const float*)d_in[12];
    const float* l1f_b   = (const float*)d_in[13];
    const float* l1b_Wih = (const float*)d_in[14];
    const float* l1b_Whh = (const float*)d_in[15];
    const float* l1b_b   = (const float*)d_in[16];
    const float* ua_W    = (const float*)d_in[17];
    const float* ua_b    = (const float*)d_in[18];
    const float* wa_W    = (const float*)d_in[19];
    const float* wa_b    = (const float*)d_in[20];
    const float* va_W    = (const float*)d_in[21];

    float* ws   = (float*)d_ws;
    float* x0   = ws + OFF_X0;
    float* gf   = ws + OFF_GF;   // also g1f, then ua
    float* gb   = ws + OFF_GB;   // also g1b, then wa
    float* h1   = ws + OFF_H1;
    float* out2 = ws + OFF_OUT2;
    float* sc   = ws + OFF_SC;
    float* nllb = ws + OFF_NLL;
    int*   cnt  = (int*)(ws + OFF_CNT);
    unsigned short* exhi = (unsigned short*)(ws + OFF_EXH);
    unsigned short* exlo = exhi + EX_U16_PER_PLANE;
    float* outf = (float*)d_out;

    hipMemsetAsync(cnt, 0, 1600 * sizeof(int), stream);
    // zero exchange planes (keeps padded-K tail zero so 0*tail can't make NaN)
    hipMemsetAsync(exhi, 0, 2 * EX_U16_PER_PLANE * sizeof(unsigned short), stream);

    embed_kernel<<<dim3((BB * SS * DIN0 + 255) / 256), 256, 0, stream>>>(
        tok, pos, word_W, pos_W, x0);

    // layer-0 input projections
    gemm_nt_bias<<<dim3(25, 25), 256, 0, stream>>>(x0, l0f_Wih, l0f_b, gf, 1600, DIN0, G4);
    gemm_nt_bias<<<dim3(25, 25), 256, 0, stream>>>(x0, l0b_Wih, l0b_b, gb, 1600, DIN0, G4);
    // layer-0 recurrence
    lstm_layer_kernel<<<dim3(200), 64, 0, stream>>>(
        gf, gb, l0f_Whh, l0b_Whh, h1, cnt, exhi, exlo);
    // layer-1 input projections
    gemm_nt_bias<<<dim3(25, 25), 256, 0, stream>>>(h1, l1f_Wih, l1f_b, gf, 1600, H2, G4);
    gemm_nt_bias<<<dim3(25, 25), 256, 0, stream>>>(h1, l1b_Wih, l1b_b, gb, 1600, H2, G4);
    // layer-1 recurrence (reuses exchange region; counters at +800)
    lstm_layer_kernel<<<dim3(200), 64, 0, stream>>>(
        gf, gb, l1f_Whh, l1b_Whh, out2, cnt + 800, exhi, exlo);
    // attention projections (reuse gf/gb slots)
    gemm_nt_bias<<<dim3(13, 25), 256, 0, stream>>>(out2, ua_W, ua_b, gf, 1600, H2, H2);
    gemm_nt_bias<<<dim3(13, 25), 256, 0, stream>>>(out2, wa_W, wa_b, gb, 1600, H2, H2);
    // scores, softmax/table/preds/nll, loss
    attn_scores_kernel<<<dim3(16 * 9), 256, 0, stream>>>(gf, gb, va_W, sc);
    attn_softmax_kernel<<<dim3(1584), 128, 0, stream>>>(sc, out2, head, outf, nllb);
    loss_kernel<<<dim3(1), 128, 0, stream>>>(nllb, head, outf);
}